// Round 2
// baseline (466.734 us; speedup 1.0000x reference)
//
#include <hip/hip_runtime.h>
#include <hip/hip_bf16.h>

#define NN 50000
#define EE 1600000

// ---------------- K1: h = elu(x) @ W ; a_src/a_dst per node ----------------
// block = 256 threads = 4 waves; wave r handles row row0+r; lane = out col c in [0,64)
__global__ __launch_bounds__(256) void k_proj(
    const float* __restrict__ x, const float* __restrict__ W,
    const float* __restrict__ att_src, const float* __restrict__ att_dst,
    float* __restrict__ h, float* __restrict__ a_src, float* __restrict__ a_dst) {
  __shared__ float Wl[128 * 64];
  __shared__ float xs[4 * 128];
  int tid = threadIdx.x;
  for (int i = tid; i < 128 * 64; i += 256) Wl[i] = W[i];
  int row0 = blockIdx.x * 4;
  for (int i = tid; i < 4 * 128; i += 256) {
    float v = x[row0 * 128 + i];
    xs[i] = v > 0.f ? v : (__expf(v) - 1.f);   // ELU
  }
  __syncthreads();
  int r = tid >> 6, c = tid & 63;
  float acc = 0.f;
#pragma unroll 8
  for (int k = 0; k < 128; ++k) acc += xs[r * 128 + k] * Wl[k * 64 + c];
  int row = row0 + r;
  h[row * 64 + c] = acc;
  int head = c >> 5, cc = c & 31;
  float ps = acc * att_src[head * 32 + cc];
  float pd = acc * att_dst[head * 32 + cc];
#pragma unroll
  for (int o = 16; o > 0; o >>= 1) {     // reduce within each 32-lane head group
    ps += __shfl_xor(ps, o);
    pd += __shfl_xor(pd, o);
  }
  if (cc == 0) {
    a_src[row * 2 + head] = ps;
    a_dst[row * 2 + head] = pd;
  }
}

// ---------------- K2: histogram of dst ----------------
__global__ __launch_bounds__(256) void k_hist(const int* __restrict__ dst,
                                              int* __restrict__ counts) {
  int e = blockIdx.x * 256 + threadIdx.x;
  atomicAdd(&counts[dst[e]], 1);
}

// ---------------- K3: exclusive scan (single block, 1024 thr) ----------------
__global__ __launch_bounds__(1024) void k_scan(const int* __restrict__ counts,
                                               int* __restrict__ offsets,
                                               int* __restrict__ cursor) {
  __shared__ int wsum[16];
  int tid = threadIdx.x, lane = tid & 63, wid = tid >> 6;
  int carry = 0;
  for (int base = 0; base < NN; base += 1024) {
    int i = base + tid;
    int v = (i < NN) ? counts[i] : 0;
    int inc = v;
#pragma unroll
    for (int o = 1; o < 64; o <<= 1) {   // wave-level inclusive scan
      int t = __shfl_up(inc, o);
      if (lane >= o) inc += t;
    }
    if (lane == 63) wsum[wid] = inc;
    __syncthreads();
    if (tid < 16) {                       // scan the 16 wave totals
      int w = wsum[tid];
#pragma unroll
      for (int o = 1; o < 16; o <<= 1) {
        int t = __shfl_up(w, o);
        if (tid >= o) w += t;
      }
      wsum[tid] = w;
    }
    __syncthreads();
    int wprefix = (wid > 0) ? wsum[wid - 1] : 0;
    int excl = carry + wprefix + inc - v;
    if (i < NN) { offsets[i] = excl; cursor[i] = excl; }
    carry += wsum[15];
    __syncthreads();                      // wsum reused next iteration
  }
  if (tid == 0) offsets[NN] = carry;      // == EE
}

// ---------------- K4: scatter src indices into CSR slots ----------------
__global__ __launch_bounds__(256) void k_scatter(const int* __restrict__ src,
                                                 const int* __restrict__ dst,
                                                 int* __restrict__ cursor,
                                                 int* __restrict__ csr) {
  int e = blockIdx.x * 256 + threadIdx.x;
  int d = dst[e];
  int pos = atomicAdd(&cursor[d], 1);
  csr[pos] = src[e];
}

// ---------------- K5: fused softmax-denominator + weighted aggregate ----------------
// one wave per dst node; lane = head*32 + c output element; denominator fused:
// out = (e_self*h[n] + sum_e e*h[src]) / sum(e)
__global__ __launch_bounds__(256) void k_agg(
    const float* __restrict__ h, const float* __restrict__ a_src,
    const float* __restrict__ a_dst, const int* __restrict__ offsets,
    const int* __restrict__ csr, const float* __restrict__ bias,
    float* __restrict__ out) {
  int n = blockIdx.x * 4 + (threadIdx.x >> 6);
  int lane = threadIdx.x & 63;
  int head = lane >> 5;
  float ad = a_dst[n * 2 + head];
  // self loop (src = n), added by PyG add_self_loops
  float l0 = a_src[n * 2 + head] + ad;
  l0 = l0 >= 0.f ? l0 : 0.2f * l0;
  float e0 = __expf(l0);
  float denom = e0;
  float acc = e0 * h[n * 64 + lane];
  int beg = offsets[n], end = offsets[n + 1];
  for (int j = beg; j < end; j += 64) {
    int cnt = min(64, end - j);
    int sidx = (lane < cnt) ? csr[j + lane] : 0;   // coalesced chunk of edge srcs
    for (int t = 0; t < cnt; ++t) {
      int s = __shfl(sidx, t);
      float ll = a_src[s * 2 + head] + ad;
      ll = ll >= 0.f ? ll : 0.2f * ll;
      float ee = __expf(ll);
      denom += ee;
      acc += ee * h[s * 64 + lane];
    }
  }
  float o = acc / (denom + 1e-16f) + bias[lane];
  out[n * 64 + lane] = o;
}

extern "C" void kernel_launch(void* const* d_in, const int* in_sizes, int n_in,
                              void* d_out, int out_size, void* d_ws, size_t ws_size,
                              hipStream_t stream) {
  const float* x       = (const float*)d_in[0];
  const float* W       = (const float*)d_in[1];
  const float* att_src = (const float*)d_in[2];
  const float* att_dst = (const float*)d_in[3];
  const float* bias    = (const float*)d_in[4];
  const int* edge_index = (const int*)d_in[5];
  const int* esrc = edge_index;        // edge_index[0, :]
  const int* edst = edge_index + EE;   // edge_index[1, :]

  float* fws = (float*)d_ws;
  int*   iws = (int*)d_ws;
  float* h       = fws;                 // 3,200,000 f32
  float* a_src_b = fws + 3200000;       //   100,000 f32
  float* a_dst_b = fws + 3300000;       //   100,000 f32
  int*   counts  = iws + 3400000;       //    50,000 i32
  int*   offsets = iws + 3450000;       //    50,001 i32
  int*   cursor  = iws + 3500004;       //    50,000 i32
  int*   csr     = iws + 3550004;       // 1,600,000 i32  (total ~20.6 MB)

  hipMemsetAsync(counts, 0, NN * sizeof(int), stream);
  k_proj<<<NN / 4, 256, 0, stream>>>(x, W, att_src, att_dst, h, a_src_b, a_dst_b);
  k_hist<<<EE / 256, 256, 0, stream>>>(edst, counts);
  k_scan<<<1, 1024, 0, stream>>>(counts, offsets, cursor);
  k_scatter<<<EE / 256, 256, 0, stream>>>(esrc, edst, cursor, csr);
  k_agg<<<NN / 4, 256, 0, stream>>>(h, a_src_b, a_dst_b, offsets, csr, bias,
                                    (float*)d_out);
}

// Round 3
// 291.866 us; speedup vs baseline: 1.5991x; 1.5991x over previous
//
#include <hip/hip_runtime.h>

#define NN 50000
#define EE 1600000

// ---------------- K1: h = elu(x) @ W ; a_src/a_dst per node ----------------
// 256 thr = 4 waves; 16 rows/block (4 rows per wave) to amortize W staging.
__global__ __launch_bounds__(256) void k_proj(
    const float* __restrict__ x, const float* __restrict__ W,
    const float* __restrict__ att_src, const float* __restrict__ att_dst,
    float* __restrict__ h, float* __restrict__ a_src, float* __restrict__ a_dst) {
  __shared__ float Wl[128 * 64];   // 32 KB
  __shared__ float xs[16 * 128];   //  8 KB
  int tid = threadIdx.x;
  for (int i = tid; i < 128 * 64; i += 256) Wl[i] = W[i];
  int row0 = blockIdx.x * 16;
  for (int i = tid; i < 16 * 128; i += 256) {
    float v = x[row0 * 128 + i];
    xs[i] = v > 0.f ? v : (__expf(v) - 1.f);   // ELU
  }
  __syncthreads();
  int w = tid >> 6, c = tid & 63;
  float acc[4] = {0.f, 0.f, 0.f, 0.f};
#pragma unroll 4
  for (int k = 0; k < 128; ++k) {
    float wv = Wl[k * 64 + c];
#pragma unroll
    for (int j = 0; j < 4; ++j) acc[j] += xs[(w * 4 + j) * 128 + k] * wv;
  }
  int hh = c >> 5, cc = c & 31;
  float asv = att_src[hh * 32 + cc], adv = att_dst[hh * 32 + cc];
#pragma unroll
  for (int j = 0; j < 4; ++j) {
    int row = row0 + w * 4 + j;
    h[row * 64 + c] = acc[j];
    float ps = acc[j] * asv, pd = acc[j] * adv;
#pragma unroll
    for (int o = 16; o > 0; o >>= 1) {   // reduce within each 32-lane head group
      ps += __shfl_xor(ps, o);
      pd += __shfl_xor(pd, o);
    }
    if (cc == 0) { a_src[row * 2 + hh] = ps; a_dst[row * 2 + hh] = pd; }
  }
}

// ---------------- K2: build 4 linked sublists per dst node ----------------
// ALL writes coalesced (next[] indexed by e); only atomicExch is random (800 KB).
__global__ __launch_bounds__(256) void k_build(const int* __restrict__ dst,
                                               int* __restrict__ headA,
                                               int* __restrict__ nxt) {
  int e = blockIdx.x * 256 + threadIdx.x;
  int d = dst[e];
  int old = atomicExch(&headA[d * 4 + (e & 3)], e);
  nxt[e] = old;
}

// ---------------- K3: fused softmax-denominator + weighted aggregate ----------------
// one wave per dst node; lane = head*32 + c output element.
// 4 independent list chases per wave overlap the dependent-load latency.
__global__ __launch_bounds__(256) void k_agg(
    const float* __restrict__ h, const float* __restrict__ a_src,
    const float* __restrict__ a_dst, const int* __restrict__ headA,
    const int* __restrict__ nxt, const int* __restrict__ srcv,
    const float* __restrict__ bias, float* __restrict__ out) {
  int n = blockIdx.x * 4 + (threadIdx.x >> 6);
  int lane = threadIdx.x & 63;
  int hh = lane >> 5;
  float ad = a_dst[n * 2 + hh];
  // self loop (src = n), added by PyG add_self_loops
  float l0 = a_src[n * 2 + hh] + ad;
  l0 = l0 >= 0.f ? l0 : 0.2f * l0;
  float es = __expf(l0);
  float denom = es;
  float acc = es * h[n * 64 + lane];
  int e0 = headA[n * 4 + 0], e1 = headA[n * 4 + 1];
  int e2 = headA[n * 4 + 2], e3 = headA[n * 4 + 3];
  while (max(max(e0, e1), max(e2, e3)) >= 0) {
    // branchless: invalid chains read index 0 and contribute weight 0
    int i0 = e0 >= 0 ? e0 : 0, i1 = e1 >= 0 ? e1 : 0;
    int i2 = e2 >= 0 ? e2 : 0, i3 = e3 >= 0 ? e3 : 0;
    int s0 = srcv[i0], n0 = nxt[i0];
    int s1 = srcv[i1], n1 = nxt[i1];
    int s2 = srcv[i2], n2 = nxt[i2];
    int s3 = srcv[i3], n3 = nxt[i3];
    float a0 = a_src[s0 * 2 + hh], a1 = a_src[s1 * 2 + hh];
    float a2 = a_src[s2 * 2 + hh], a3 = a_src[s3 * 2 + hh];
    float h0 = h[s0 * 64 + lane], h1 = h[s1 * 64 + lane];
    float h2 = h[s2 * 64 + lane], h3 = h[s3 * 64 + lane];
    float l;
    l = a0 + ad; l = l >= 0.f ? l : 0.2f * l; float x0 = e0 >= 0 ? __expf(l) : 0.f;
    l = a1 + ad; l = l >= 0.f ? l : 0.2f * l; float x1 = e1 >= 0 ? __expf(l) : 0.f;
    l = a2 + ad; l = l >= 0.f ? l : 0.2f * l; float x2 = e2 >= 0 ? __expf(l) : 0.f;
    l = a3 + ad; l = l >= 0.f ? l : 0.2f * l; float x3 = e3 >= 0 ? __expf(l) : 0.f;
    denom += (x0 + x1) + (x2 + x3);
    acc += x0 * h0 + x1 * h1 + x2 * h2 + x3 * h3;
    e0 = e0 >= 0 ? n0 : -1; e1 = e1 >= 0 ? n1 : -1;
    e2 = e2 >= 0 ? n2 : -1; e3 = e3 >= 0 ? n3 : -1;
  }
  out[n * 64 + lane] = acc / (denom + 1e-16f) + bias[lane];
}

extern "C" void kernel_launch(void* const* d_in, const int* in_sizes, int n_in,
                              void* d_out, int out_size, void* d_ws, size_t ws_size,
                              hipStream_t stream) {
  const float* x       = (const float*)d_in[0];
  const float* W       = (const float*)d_in[1];
  const float* att_src = (const float*)d_in[2];
  const float* att_dst = (const float*)d_in[3];
  const float* bias    = (const float*)d_in[4];
  const int* edge_index = (const int*)d_in[5];
  const int* esrc = edge_index;        // edge_index[0, :]
  const int* edst = edge_index + EE;   // edge_index[1, :]

  float* fws = (float*)d_ws;
  int*   iws = (int*)d_ws;
  float* h       = fws;                 // 3,200,000 f32 (12.8 MB)
  float* a_src_b = fws + 3200000;       //   100,000 f32
  float* a_dst_b = fws + 3300000;       //   100,000 f32
  int*   headA   = iws + 3400000;       //   200,000 i32 (4 sublists/node)
  int*   nxt     = iws + 3600000;       // 1,600,000 i32 (total ~20.8 MB)

  hipMemsetAsync(headA, 0xFF, 200000 * sizeof(int), stream);   // -1 sentinels
  k_proj<<<NN / 16, 256, 0, stream>>>(x, W, att_src, att_dst, h, a_src_b, a_dst_b);
  k_build<<<EE / 256, 256, 0, stream>>>(edst, headA, nxt);
  k_agg<<<NN / 4, 256, 0, stream>>>(h, a_src_b, a_dst_b, headA, nxt, esrc, bias,
                                    (float*)d_out);
}

// Round 4
// 264.493 us; speedup vs baseline: 1.7646x; 1.1035x over previous
//
#include <hip/hip_runtime.h>
#include <hip/hip_bf16.h>

#define NN 50000
#define EE 1600000

__device__ __forceinline__ float bflo(unsigned u) { return __uint_as_float(u << 16); }
__device__ __forceinline__ float bfhi(unsigned u) { return __uint_as_float(u & 0xffff0000u); }

// ---------------- K1: h = elu(x) @ W (stored bf16) ; a_src/a_dst per node ----------------
// 256 thr = 4 waves; 16 rows/block (4 rows per wave) to amortize W staging.
__global__ __launch_bounds__(256) void k_proj(
    const float* __restrict__ x, const float* __restrict__ W,
    const float* __restrict__ att_src, const float* __restrict__ att_dst,
    unsigned short* __restrict__ h2, float* __restrict__ a_src, float* __restrict__ a_dst) {
  __shared__ float Wl[128 * 64];   // 32 KB
  __shared__ float xs[16 * 128];   //  8 KB
  int tid = threadIdx.x;
  for (int i = tid; i < 128 * 64; i += 256) Wl[i] = W[i];
  int row0 = blockIdx.x * 16;
  for (int i = tid; i < 16 * 128; i += 256) {
    float v = x[row0 * 128 + i];
    xs[i] = v > 0.f ? v : (__expf(v) - 1.f);   // ELU
  }
  __syncthreads();
  int w = tid >> 6, c = tid & 63;
  float acc[4] = {0.f, 0.f, 0.f, 0.f};
#pragma unroll 4
  for (int k = 0; k < 128; ++k) {
    float wv = Wl[k * 64 + c];
#pragma unroll
    for (int j = 0; j < 4; ++j) acc[j] += xs[(w * 4 + j) * 128 + k] * wv;
  }
  int hh = c >> 5, cc = c & 31;
  float asv = att_src[hh * 32 + cc], adv = att_dst[hh * 32 + cc];
#pragma unroll
  for (int j = 0; j < 4; ++j) {
    int row = row0 + w * 4 + j;
    h2[row * 64 + c] = __bfloat16_as_ushort(__float2bfloat16(acc[j]));
    float ps = acc[j] * asv, pd = acc[j] * adv;
#pragma unroll
    for (int o = 16; o > 0; o >>= 1) {   // reduce within each 32-lane head group
      ps += __shfl_xor(ps, o);
      pd += __shfl_xor(pd, o);
    }
    if (cc == 0) { a_src[row * 2 + hh] = ps; a_dst[row * 2 + hh] = pd; }
  }
}

// ---------------- K2: build 4 linked sublists per dst node ----------------
// ALL stores coalesced (nxt[] indexed by e); only atomicExch is random (800 KB).
__global__ __launch_bounds__(256) void k_build(const int* __restrict__ dst,
                                               int* __restrict__ headA,
                                               int* __restrict__ nxt) {
  int e = blockIdx.x * 256 + threadIdx.x;
  int d = dst[e];
  int old = atomicExch(&headA[d * 4 + (e & 3)], e);
  nxt[e] = old;
}

// ---------------- K3: fused softmax-denominator + weighted aggregate ----------------
// one wave per dst node. Half-wave split: lanes 0-31 chase chains {0,1},
// lanes 32-63 chains {2,3}. Each lane owns 2 output columns via one bf16x2 load.
__global__ __launch_bounds__(256) void k_agg(
    const unsigned* __restrict__ h2u, const float* __restrict__ a_src,
    const float* __restrict__ a_dst, const int* __restrict__ headA,
    const int* __restrict__ nxt, const int* __restrict__ srcv,
    const float* __restrict__ bias, float* __restrict__ out) {
  int n = blockIdx.x * 4 + (threadIdx.x >> 6);
  int lane = threadIdx.x & 63;
  int c2 = lane & 31;          // column pair index: cols 2*c2, 2*c2+1
  int half = lane >> 5;        // which half-wave
  int hh = c2 >> 4;            // head of this column pair
  float ad = a_dst[n * 2 + hh];

  float denom, acc0, acc1;
  if (half == 0) {
    // self loop (src = n), added by PyG add_self_loops — counted once (half 0)
    float l0 = a_src[n * 2 + hh] + ad;
    l0 = fmaxf(l0, 0.2f * l0);
    float es = __expf(l0);
    unsigned hv = h2u[n * 32 + c2];
    denom = es; acc0 = es * bflo(hv); acc1 = es * bfhi(hv);
  } else {
    denom = 0.f; acc0 = 0.f; acc1 = 0.f;
  }

  int eA = headA[n * 4 + 2 * half];
  int eB = headA[n * 4 + 2 * half + 1];
  while (__any(max(eA, eB) >= 0)) {
    int iA = max(eA, 0), iB = max(eB, 0);     // dead chains read slot 0, weight 0
    int sA = srcv[iA], sB = srcv[iB];
    int nA = nxt[iA],  nB = nxt[iB];
    unsigned hA = h2u[sA * 32 + c2], hB = h2u[sB * 32 + c2];
    float aA = a_src[sA * 2 + hh],  aB = a_src[sB * 2 + hh];
    float lA = aA + ad; lA = fmaxf(lA, 0.2f * lA);
    float lB = aB + ad; lB = fmaxf(lB, 0.2f * lB);
    float xA = (eA >= 0) ? __expf(lA) : 0.f;
    float xB = (eB >= 0) ? __expf(lB) : 0.f;
    denom += xA + xB;
    acc0 += xA * bflo(hA) + xB * bflo(hB);
    acc1 += xA * bfhi(hA) + xB * bfhi(hB);
    eA = (eA >= 0) ? nA : -1;
    eB = (eB >= 0) ? nB : -1;
  }
  // merge the two half-waves (paired lanes own the same columns)
  denom += __shfl_xor(denom, 32);
  acc0  += __shfl_xor(acc0, 32);
  acc1  += __shfl_xor(acc1, 32);
  if (half == 0) {
    float inv = 1.f / (denom + 1e-16f);
    float2 b = ((const float2*)bias)[c2];
    float2 o;
    o.x = acc0 * inv + b.x;
    o.y = acc1 * inv + b.y;
    ((float2*)out)[n * 32 + c2] = o;
  }
}

extern "C" void kernel_launch(void* const* d_in, const int* in_sizes, int n_in,
                              void* d_out, int out_size, void* d_ws, size_t ws_size,
                              hipStream_t stream) {
  const float* x       = (const float*)d_in[0];
  const float* W       = (const float*)d_in[1];
  const float* att_src = (const float*)d_in[2];
  const float* att_dst = (const float*)d_in[3];
  const float* bias    = (const float*)d_in[4];
  const int* edge_index = (const int*)d_in[5];
  const int* esrc = edge_index;        // edge_index[0, :]
  const int* edst = edge_index + EE;   // edge_index[1, :]

  char* base = (char*)d_ws;
  unsigned short* h2 = (unsigned short*)base;            // 3.2M bf16 (6.4 MB)
  float* a_src_b = (float*)(base + 6400000);             // 100K f32
  float* a_dst_b = (float*)(base + 6800000);             // 100K f32
  int*   headA   = (int*)(base + 7200000);               // 200K i32
  int*   nxt     = (int*)(base + 8000000);               // 1.6M i32 (total 14.4 MB)

  hipMemsetAsync(headA, 0xFF, 200000 * sizeof(int), stream);   // -1 sentinels
  k_proj<<<NN / 16, 256, 0, stream>>>(x, W, att_src, att_dst, h2, a_src_b, a_dst_b);
  k_build<<<EE / 256, 256, 0, stream>>>(edst, headA, nxt);
  k_agg<<<NN / 4, 256, 0, stream>>>((const unsigned*)h2, a_src_b, a_dst_b, headA,
                                    nxt, esrc, bias, (float*)d_out);
}

// Round 6
// 261.953 us; speedup vs baseline: 1.7817x; 1.0097x over previous
//
#include <hip/hip_runtime.h>
#include <hip/hip_bf16.h>

#define NN 50000
#define EE 1600000

__device__ __forceinline__ float bflo(unsigned u) { return __uint_as_float(u << 16); }
__device__ __forceinline__ float bfhi(unsigned u) { return __uint_as_float(u & 0xffff0000u); }

// ---------------- K1: h = elu(x) @ W (stored bf16-packed) ; a_src/a_dst ----------------
// block 256 = 4 waves, 32 rows/block (8/wave). Lane = rs*32+c: cols {2c,2c+1},
// rows rs*4+j. Per k: one ds_read_b64 of W feeds 8 FMAs; xs padded to stride 129.
__global__ __launch_bounds__(256) void k_proj(
    const float* __restrict__ x, const float* __restrict__ W,
    const float* __restrict__ att_src, const float* __restrict__ att_dst,
    unsigned* __restrict__ h2u, float* __restrict__ a_src, float* __restrict__ a_dst) {
  __shared__ float Wl[128 * 64];   // [k][c] row-major, 32 KB; float2 view = col pairs
  __shared__ float xs[32 * 129];   // 32 rows, padded, 16.5 KB
  int tid = threadIdx.x;
  int row0 = blockIdx.x * 32;
  for (int i = tid; i < 128 * 64; i += 256) Wl[i] = W[i];
  for (int i = tid; i < 32 * 128; i += 256) {
    int r = i >> 7, k = i & 127;
    int row = row0 + r;
    float v = (row < NN) ? x[row * 128 + k] : 0.f;
    xs[r * 129 + k] = v > 0.f ? v : (__expf(v) - 1.f);   // ELU
  }
  __syncthreads();
  int w = tid >> 6, lane = tid & 63;
  int rs = lane >> 5, c = lane & 31;
  int rbase = w * 8 + rs * 4;                 // block-local rows rbase..rbase+3
  float a0[4] = {0, 0, 0, 0}, a1[4] = {0, 0, 0, 0};
  const float2* W2 = (const float2*)Wl;
#pragma unroll 4
  for (int k = 0; k < 128; ++k) {
    float2 wv = W2[k * 32 + c];
#pragma unroll
    for (int j = 0; j < 4; ++j) {
      float xv = xs[(rbase + j) * 129 + k];
      a0[j] += xv * wv.x;
      a1[j] += xv * wv.y;
    }
  }
  int hh = c >> 4;
  float2 av_s = ((const float2*)att_src)[c];  // cols 2c,2c+1 of flat [2][32]
  float2 av_d = ((const float2*)att_dst)[c];
#pragma unroll
  for (int j = 0; j < 4; ++j) {
    int row = row0 + rbase + j;
    bool ok = row < NN;
    if (ok) {
      unsigned lo = (unsigned)__bfloat16_as_ushort(__float2bfloat16(a0[j]));
      unsigned hi = (unsigned)__bfloat16_as_ushort(__float2bfloat16(a1[j]));
      h2u[row * 32 + c] = lo | (hi << 16);
    }
    float ps = a0[j] * av_s.x + a1[j] * av_s.y;
    float pd = a0[j] * av_d.x + a1[j] * av_d.y;
#pragma unroll
    for (int o = 1; o < 16; o <<= 1) {        // reduce 16 lanes of this head group
      ps += __shfl_xor(ps, o);
      pd += __shfl_xor(pd, o);
    }
    if (ok && (c & 15) == 0) { a_src[row * 2 + hh] = ps; a_dst[row * 2 + hh] = pd; }
  }
}

// ---------------- K2: build 8 linked sublists per dst node ----------------
// Coalesced read of src/dst, coalesced int2 write; only atomicExch is random.
__global__ __launch_bounds__(256) void k_build(const int* __restrict__ src,
                                               const int* __restrict__ dst,
                                               int* __restrict__ head8,
                                               int2* __restrict__ edge2) {
  int e = blockIdx.x * 256 + threadIdx.x;
  int d = dst[e];
  int old = atomicExch(&head8[d * 8 + (e & 7)], e);
  edge2[e] = make_int2(src[e], old);
}

// ---------------- K3: fused softmax-denominator + weighted aggregate ----------------
// one wave per dst node; each half-wave chases 4 chains; (src,next) in one int2
// so each chase step touches ONE cache line instead of two.
__global__ __launch_bounds__(256) void k_agg(
    const unsigned* __restrict__ h2u, const float* __restrict__ a_src,
    const float* __restrict__ a_dst, const int* __restrict__ head8,
    const int2* __restrict__ edge2, const float* __restrict__ bias,
    float* __restrict__ out) {
  int n = blockIdx.x * 4 + (threadIdx.x >> 6);
  int lane = threadIdx.x & 63;
  int c2 = lane & 31;          // column pair: cols 2*c2, 2*c2+1
  int half = lane >> 5;
  int hh = c2 >> 4;
  float ad = a_dst[n * 2 + hh];

  float denom = 0.f, acc0 = 0.f, acc1 = 0.f;
  if (half == 0) {             // self loop (PyG add_self_loops), counted once
    float l0 = a_src[n * 2 + hh] + ad;
    l0 = fmaxf(l0, 0.2f * l0);
    float es = __expf(l0);
    unsigned hv = h2u[n * 32 + c2];
    denom = es; acc0 = es * bflo(hv); acc1 = es * bfhi(hv);
  }

  int e0 = head8[n * 8 + half * 4 + 0];
  int e1 = head8[n * 8 + half * 4 + 1];
  int e2 = head8[n * 8 + half * 4 + 2];
  int e3 = head8[n * 8 + half * 4 + 3];
  while (__any(max(max(e0, e1), max(e2, e3)) >= 0)) {
    int2 p0 = edge2[max(e0, 0)];
    int2 p1 = edge2[max(e1, 0)];
    int2 p2 = edge2[max(e2, 0)];
    int2 p3 = edge2[max(e3, 0)];
    unsigned h0 = h2u[p0.x * 32 + c2], h1 = h2u[p1.x * 32 + c2];
    unsigned h2 = h2u[p2.x * 32 + c2], h3 = h2u[p3.x * 32 + c2];
    float A0 = a_src[p0.x * 2 + hh], A1 = a_src[p1.x * 2 + hh];
    float A2 = a_src[p2.x * 2 + hh], A3 = a_src[p3.x * 2 + hh];
    float l;
    l = A0 + ad; l = fmaxf(l, 0.2f * l); float x0 = (e0 >= 0) ? __expf(l) : 0.f;
    l = A1 + ad; l = fmaxf(l, 0.2f * l); float x1 = (e1 >= 0) ? __expf(l) : 0.f;
    l = A2 + ad; l = fmaxf(l, 0.2f * l); float x2 = (e2 >= 0) ? __expf(l) : 0.f;
    l = A3 + ad; l = fmaxf(l, 0.2f * l); float x3 = (e3 >= 0) ? __expf(l) : 0.f;
    denom += (x0 + x1) + (x2 + x3);
    acc0 += x0 * bflo(h0) + x1 * bflo(h1) + x2 * bflo(h2) + x3 * bflo(h3);
    acc1 += x0 * bfhi(h0) + x1 * bfhi(h1) + x2 * bfhi(h2) + x3 * bfhi(h3);
    e0 = (e0 >= 0) ? p0.y : -1;
    e1 = (e1 >= 0) ? p1.y : -1;
    e2 = (e2 >= 0) ? p2.y : -1;
    e3 = (e3 >= 0) ? p3.y : -1;
  }
  denom += __shfl_xor(denom, 32);
  acc0  += __shfl_xor(acc0, 32);
  acc1  += __shfl_xor(acc1, 32);
  if (half == 0) {
    float inv = 1.f / (denom + 1e-16f);
    float2 b = ((const float2*)bias)[c2];
    ((float2*)out)[n * 32 + c2] = make_float2(acc0 * inv + b.x, acc1 * inv + b.y);
  }
}

extern "C" void kernel_launch(void* const* d_in, const int* in_sizes, int n_in,
                              void* d_out, int out_size, void* d_ws, size_t ws_size,
                              hipStream_t stream) {
  const float* x       = (const float*)d_in[0];
  const float* W       = (const float*)d_in[1];
  const float* att_src = (const float*)d_in[2];
  const float* att_dst = (const float*)d_in[3];
  const float* bias    = (const float*)d_in[4];
  const int* edge_index = (const int*)d_in[5];
  const int* esrc = edge_index;        // edge_index[0, :]
  const int* edst = edge_index + EE;   // edge_index[1, :]

  // Workspace layout (NOTE: a_src/a_dst are 100K floats = 400,000 B EACH):
  char* base = (char*)d_ws;
  unsigned* h2u  = (unsigned*)base;                      // [0        .. 6,400,000)  h bf16x2
  float* a_src_b = (float*)(base + 6400000);             // [6.4M     .. 6.8M)
  float* a_dst_b = (float*)(base + 6800000);             // [6.8M     .. 7.2M)
  int*   head8   = (int*)(base + 7200000);               // [7.2M     .. 8.8M)  400K i32
  int2*  edge2   = (int2*)(base + 8800000);              // [8.8M     .. 21.6M) 1.6M int2

  hipMemsetAsync(head8, 0xFF, 400000 * sizeof(int), stream);   // -1 sentinels
  k_proj<<<(NN + 31) / 32, 256, 0, stream>>>(x, W, att_src, att_dst, h2u,
                                             a_src_b, a_dst_b);
  k_build<<<EE / 256, 256, 0, stream>>>(esrc, edst, head8, edge2);
  k_agg<<<NN / 4, 256, 0, stream>>>(h2u, a_src_b, a_dst_b, head8, edge2, bias,
                                    (float*)d_out);
}

// Round 7
// 249.959 us; speedup vs baseline: 1.8672x; 1.0480x over previous
//
#include <hip/hip_runtime.h>
#include <hip/hip_bf16.h>

#define NN 50000
#define EE 1600000

__device__ __forceinline__ float bflo(unsigned u) { return __uint_as_float(u << 16); }
__device__ __forceinline__ float bfhi(unsigned u) { return __uint_as_float(u & 0xffff0000u); }

// ---------------- K1: h = elu(x) @ W (stored bf16-packed) ; a_src/a_dst ----------------
// block 256 = 4 waves, 32 rows/block (8/wave). Lane = rs*32+c: cols {2c,2c+1},
// rows rs*4+j. Per k: one ds_read_b64 of W feeds 8 FMAs; xs reads are broadcasts.
__global__ __launch_bounds__(256) void k_proj(
    const float* __restrict__ x, const float* __restrict__ W,
    const float* __restrict__ att_src, const float* __restrict__ att_dst,
    unsigned* __restrict__ h2u, float* __restrict__ a_src, float* __restrict__ a_dst) {
  __shared__ float Wl[128 * 64];   // [k][c] row-major, 32 KB; float2 view = col pairs
  __shared__ float xs[32 * 129];   // 32 rows, padded, 16.5 KB
  int tid = threadIdx.x;
  int row0 = blockIdx.x * 32;
  for (int i = tid; i < 128 * 64; i += 256) Wl[i] = W[i];
  for (int i = tid; i < 32 * 128; i += 256) {
    int r = i >> 7, k = i & 127;
    int row = row0 + r;
    float v = (row < NN) ? x[row * 128 + k] : 0.f;
    xs[r * 129 + k] = v > 0.f ? v : (__expf(v) - 1.f);   // ELU
  }
  __syncthreads();
  int w = tid >> 6, lane = tid & 63;
  int rs = lane >> 5, c = lane & 31;
  int rbase = w * 8 + rs * 4;                 // block-local rows rbase..rbase+3
  float a0[4] = {0, 0, 0, 0}, a1[4] = {0, 0, 0, 0};
  const float2* W2 = (const float2*)Wl;
#pragma unroll 4
  for (int k = 0; k < 128; ++k) {
    float2 wv = W2[k * 32 + c];
#pragma unroll
    for (int j = 0; j < 4; ++j) {
      float xv = xs[(rbase + j) * 129 + k];
      a0[j] += xv * wv.x;
      a1[j] += xv * wv.y;
    }
  }
  int hh = c >> 4;
  float2 av_s = ((const float2*)att_src)[c];  // cols 2c,2c+1 of flat [2][32]
  float2 av_d = ((const float2*)att_dst)[c];
#pragma unroll
  for (int j = 0; j < 4; ++j) {
    int row = row0 + rbase + j;
    bool ok = row < NN;
    if (ok) {
      unsigned lo = (unsigned)__bfloat16_as_ushort(__float2bfloat16(a0[j]));
      unsigned hi = (unsigned)__bfloat16_as_ushort(__float2bfloat16(a1[j]));
      h2u[row * 32 + c] = lo | (hi << 16);
    }
    float ps = a0[j] * av_s.x + a1[j] * av_s.y;
    float pd = a0[j] * av_d.x + a1[j] * av_d.y;
#pragma unroll
    for (int o = 1; o < 16; o <<= 1) {        // reduce 16 lanes of this head group
      ps += __shfl_xor(ps, o);
      pd += __shfl_xor(pd, o);
    }
    if (ok && (c & 15) == 0) { a_src[row * 2 + hh] = ps; a_dst[row * 2 + hh] = pd; }
  }
}

// ---------------- K2: build lists AND precompute per-edge softmax weights ----------------
// One lane per edge (vs 16 redundant lanes in k_agg): gathers the two 8 B
// attention entries (L2-resident 800 KB tables), computes both heads' exp once,
// writes a 16 B record. Random-read line cost in k_agg is unchanged (1 line/step).
__global__ __launch_bounds__(256) void k_build(
    const int* __restrict__ src, const int* __restrict__ dst,
    const float2* __restrict__ a_src2, const float2* __restrict__ a_dst2,
    int* __restrict__ head8, int4* __restrict__ edge4) {
  int e = blockIdx.x * 256 + threadIdx.x;
  int s = src[e], d = dst[e];
  float2 as = a_src2[s], ad = a_dst2[d];
  float l0 = as.x + ad.x; l0 = fmaxf(l0, 0.2f * l0);
  float l1 = as.y + ad.y; l1 = fmaxf(l1, 0.2f * l1);
  int old = atomicExch(&head8[d * 8 + (e & 7)], e);
  edge4[e] = make_int4(s, old, __float_as_int(__expf(l0)), __float_as_int(__expf(l1)));
}

// ---------------- K3: weighted aggregate (weights precomputed) ----------------
// one wave per dst node; each half-wave chases 4 chains. Per chase step per lane:
// one int4 record load + one h load + ~10 VALU (no exp, no logit math).
__global__ __launch_bounds__(256) void k_agg(
    const unsigned* __restrict__ h2u, const float* __restrict__ a_src,
    const float* __restrict__ a_dst, const int* __restrict__ head8,
    const int4* __restrict__ edge4, const float* __restrict__ bias,
    float* __restrict__ out) {
  int n = blockIdx.x * 4 + (threadIdx.x >> 6);
  int lane = threadIdx.x & 63;
  int c2 = lane & 31;          // column pair: cols 2*c2, 2*c2+1
  int half = lane >> 5;
  int hh = c2 >> 4;

  float denom = 0.f, acc0 = 0.f, acc1 = 0.f;
  if (half == 0) {             // self loop (PyG add_self_loops), counted once
    float l0 = a_src[n * 2 + hh] + a_dst[n * 2 + hh];
    l0 = fmaxf(l0, 0.2f * l0);
    float es = __expf(l0);
    unsigned hv = h2u[n * 32 + c2];
    denom = es; acc0 = es * bflo(hv); acc1 = es * bfhi(hv);
  }

  int e0 = head8[n * 8 + half * 4 + 0];
  int e1 = head8[n * 8 + half * 4 + 1];
  int e2 = head8[n * 8 + half * 4 + 2];
  int e3 = head8[n * 8 + half * 4 + 3];
  while (__any(max(max(e0, e1), max(e2, e3)) >= 0)) {
    int4 p0 = edge4[max(e0, 0)];
    int4 p1 = edge4[max(e1, 0)];
    int4 p2 = edge4[max(e2, 0)];
    int4 p3 = edge4[max(e3, 0)];
    unsigned h0 = h2u[p0.x * 32 + c2], h1 = h2u[p1.x * 32 + c2];
    unsigned h2 = h2u[p2.x * 32 + c2], h3 = h2u[p3.x * 32 + c2];
    float x0 = (e0 >= 0) ? __int_as_float(hh ? p0.w : p0.z) : 0.f;
    float x1 = (e1 >= 0) ? __int_as_float(hh ? p1.w : p1.z) : 0.f;
    float x2 = (e2 >= 0) ? __int_as_float(hh ? p2.w : p2.z) : 0.f;
    float x3 = (e3 >= 0) ? __int_as_float(hh ? p3.w : p3.z) : 0.f;
    denom += (x0 + x1) + (x2 + x3);
    acc0 += x0 * bflo(h0) + x1 * bflo(h1) + x2 * bflo(h2) + x3 * bflo(h3);
    acc1 += x0 * bfhi(h0) + x1 * bfhi(h1) + x2 * bfhi(h2) + x3 * bfhi(h3);
    e0 = (e0 >= 0) ? p0.y : -1;
    e1 = (e1 >= 0) ? p1.y : -1;
    e2 = (e2 >= 0) ? p2.y : -1;
    e3 = (e3 >= 0) ? p3.y : -1;
  }
  denom += __shfl_xor(denom, 32);
  acc0  += __shfl_xor(acc0, 32);
  acc1  += __shfl_xor(acc1, 32);
  if (half == 0) {
    float inv = 1.f / (denom + 1e-16f);
    float2 b = ((const float2*)bias)[c2];
    ((float2*)out)[n * 32 + c2] = make_float2(acc0 * inv + b.x, acc1 * inv + b.y);
  }
}

extern "C" void kernel_launch(void* const* d_in, const int* in_sizes, int n_in,
                              void* d_out, int out_size, void* d_ws, size_t ws_size,
                              hipStream_t stream) {
  const float* x       = (const float*)d_in[0];
  const float* W       = (const float*)d_in[1];
  const float* att_src = (const float*)d_in[2];
  const float* att_dst = (const float*)d_in[3];
  const float* bias    = (const float*)d_in[4];
  const int* edge_index = (const int*)d_in[5];
  const int* esrc = edge_index;        // edge_index[0, :]
  const int* edst = edge_index + EE;   // edge_index[1, :]

  // Workspace layout (a_src/a_dst are 100K floats = 400,000 B EACH):
  char* base = (char*)d_ws;
  unsigned* h2u  = (unsigned*)base;                      // [0     .. 6.4M)   h bf16x2
  float* a_src_b = (float*)(base + 6400000);             // [6.4M  .. 6.8M)
  float* a_dst_b = (float*)(base + 6800000);             // [6.8M  .. 7.2M)
  int*   head8   = (int*)(base + 7200000);               // [7.2M  .. 8.8M)  400K i32
  int4*  edge4   = (int4*)(base + 8800000);              // [8.8M  .. 34.4M) 1.6M int4

  hipMemsetAsync(head8, 0xFF, 400000 * sizeof(int), stream);   // -1 sentinels
  k_proj<<<(NN + 31) / 32, 256, 0, stream>>>(x, W, att_src, att_dst, h2u,
                                             a_src_b, a_dst_b);
  k_build<<<EE / 256, 256, 0, stream>>>(esrc, edst, (const float2*)a_src_b,
                                        (const float2*)a_dst_b, head8, edge4);
  k_agg<<<NN / 4, 256, 0, stream>>>(h2u, a_src_b, a_dst_b, head8, edge4, bias,
                                    (float*)d_out);
}